// Round 1
// baseline (1054.345 us; speedup 1.0000x reference)
//
#include <hip/hip_runtime.h>

// Problem constants (fixed by reference):
#define NB    32          // batch
#define CCH   256         // channels
#define HW    1024        // H*W
#define NPIX  (NB*HW)     // 32768 pixels per input
#define DDICT 1024        // dictionary entries

// Output layout (flat fp32 elements, per input section):
//   emb (8388608) | emb_pt (8388608) | idx (32768)  -> section = 16809984
#define EMB_ELEMS  ((size_t)NB*CCH*HW)      // 8388608
#define SEC_ELEMS  (2*EMB_ELEMS + NPIX)     // 16809984

// Stage-1 tiling
#define BK   16
#define TPX  128   // pixels per tile
#define TD   256   // dicts per tile
#define NDT  (DDICT/TD)   // 4 d-tiles

// ---------------- Stage 0: dictionary norms ----------------
__global__ void dict_norms_kernel(const float* __restrict__ dict,
                                  float* __restrict__ norms) {
    int d = blockIdx.x * blockDim.x + threadIdx.x;
    if (d < DDICT) {
        const float4* row = (const float4*)(dict + (size_t)d * CCH);
        float s = 0.f;
#pragma unroll 8
        for (int i = 0; i < CCH / 4; ++i) {
            float4 v = row[i];
            s += v.x * v.x + v.y * v.y + v.z * v.z + v.w * v.w;
        }
        norms[d] = s;
    }
}

// ---------------- Stage 1: tiled GEMM + partial argmin ----------------
// grid: (NPIX/TPX, NDT), block: 256
__global__ __launch_bounds__(256, 2)
void vq_partial_kernel(const float* __restrict__ x,     // [NB][CCH][HW]
                       const float* __restrict__ dict,  // [DDICT][CCH]
                       const float* __restrict__ norms, // [DDICT]
                       float* __restrict__ pdist,       // [NPIX][NDT]
                       int*   __restrict__ pidx) {      // [NPIX][NDT]
    __shared__ float A_s[BK][TPX + 4];   // [k][pixel]
    __shared__ float B_s[BK][TD + 4];    // [k][dict]
    __shared__ float red_d[16][8][16];   // [ty][p][tx]
    __shared__ int   red_i[16][8][16];

    const int t  = threadIdx.x;
    const int tx = t & 15;     // dict group: 16 dicts
    const int ty = t >> 4;     // pixel group: 8 pixels

    const int g0  = blockIdx.x * TPX;    // base pixel (global)
    const int d0  = blockIdx.y * TD;     // base dict
    const int n   = g0 / HW;
    const int hw0 = g0 % HW;             // multiple of 128 -> same n for whole tile
    const float* xbase = x + (size_t)n * CCH * HW + hw0;

    float acc[8][16];
#pragma unroll
    for (int p = 0; p < 8; ++p)
#pragma unroll
        for (int j = 0; j < 16; ++j) acc[p][j] = 0.f;

    const int a_l4 = t & 31;   // float4 index within 128-px row
    const int a_row = t >> 5;  // 0..7
    const int b_c4 = t & 3;    // float4 within 16-ch chunk
    const int b_dd = t >> 2;   // 0..63

#pragma unroll 1
    for (int kc = 0; kc < CCH / BK; ++kc) {
        const int c0 = kc * BK;
        // A chunk: A_s[k][p] = x[n][c0+k][hw0+p]
#pragma unroll
        for (int pass = 0; pass < 2; ++pass) {
            int k = pass * 8 + a_row;
            float4 v = *(const float4*)(xbase + (size_t)(c0 + k) * HW + a_l4 * 4);
            *(float4*)&A_s[k][a_l4 * 4] = v;
        }
        // B chunk: B_s[k][dd] = dict[d0+dd][c0+k]
#pragma unroll
        for (int pass = 0; pass < 4; ++pass) {
            int dd = pass * 64 + b_dd;
            float4 v = *(const float4*)(dict + (size_t)(d0 + dd) * CCH + c0 + b_c4 * 4);
            B_s[b_c4 * 4 + 0][dd] = v.x;
            B_s[b_c4 * 4 + 1][dd] = v.y;
            B_s[b_c4 * 4 + 2][dd] = v.z;
            B_s[b_c4 * 4 + 3][dd] = v.w;
        }
        __syncthreads();
#pragma unroll
        for (int k = 0; k < BK; ++k) {
            float4 a0 = *(const float4*)&A_s[k][ty * 8];
            float4 a1 = *(const float4*)&A_s[k][ty * 8 + 4];
            float4 b0 = *(const float4*)&B_s[k][tx * 16];
            float4 b1 = *(const float4*)&B_s[k][tx * 16 + 4];
            float4 b2 = *(const float4*)&B_s[k][tx * 16 + 8];
            float4 b3 = *(const float4*)&B_s[k][tx * 16 + 12];
            float av[8] = {a0.x, a0.y, a0.z, a0.w, a1.x, a1.y, a1.z, a1.w};
            float bv[16] = {b0.x, b0.y, b0.z, b0.w, b1.x, b1.y, b1.z, b1.w,
                            b2.x, b2.y, b2.z, b2.w, b3.x, b3.y, b3.z, b3.w};
#pragma unroll
            for (int p = 0; p < 8; ++p)
#pragma unroll
                for (int j = 0; j < 16; ++j)
                    acc[p][j] = fmaf(av[p], bv[j], acc[p][j]);
        }
        __syncthreads();
    }

    // Epilogue: dist = norm - 2*dot, per-thread argmin over 16 dicts
    float nrm[16];
#pragma unroll
    for (int j = 0; j < 16; ++j) nrm[j] = norms[d0 + tx * 16 + j];

#pragma unroll
    for (int p = 0; p < 8; ++p) {
        float bd = 3.0e38f;
        int   bi = 0;
#pragma unroll
        for (int j = 0; j < 16; ++j) {
            float dist = fmaf(-2.f, acc[p][j], nrm[j]);
            if (dist < bd) { bd = dist; bi = tx * 16 + j; }  // ascending j: lowest idx wins ties
        }
        red_d[ty][p][tx] = bd;
        red_i[ty][p][tx] = bi;
    }
    __syncthreads();

    if (t < TPX) {   // one thread per pixel of the tile
        int tys = t >> 3, ps = t & 7;
        float best = red_d[tys][ps][0];
        int   bidx = red_i[tys][ps][0];
#pragma unroll
        for (int q = 1; q < 16; ++q) {   // ascending tx: lowest idx wins ties
            float dq = red_d[tys][ps][q];
            if (dq < best) { best = dq; bidx = red_i[tys][ps][q]; }
        }
        int g = g0 + t;
        pdist[(size_t)g * NDT + blockIdx.y] = best;
        pidx [(size_t)g * NDT + blockIdx.y] = d0 + bidx;
    }
}

// ---------------- Stage 2: final argmin + gather + writes ----------------
// grid: NPIX/32, block: 256 (32 pixels per block)
__global__ void vq_finalize_kernel(const float* __restrict__ pdist,
                                   const int*   __restrict__ pidx,
                                   const float* __restrict__ dict,
                                   float* __restrict__ out_emb,
                                   float* __restrict__ out_emb_pt,
                                   float* __restrict__ out_idx) {
    __shared__ int idx_s[32];
    const int t  = threadIdx.x;
    const int g0 = blockIdx.x * 32;

    if (t < 32) {
        int g = g0 + t;
        float best = pdist[(size_t)g * NDT + 0];
        int   bidx = pidx [(size_t)g * NDT + 0];
#pragma unroll
        for (int q = 1; q < NDT; ++q) {   // ascending tile: lowest idx wins ties
            float d = pdist[(size_t)g * NDT + q];
            if (d < best) { best = d; bidx = pidx[(size_t)g * NDT + q]; }
        }
        idx_s[t] = bidx;
        out_idx[g] = (float)bidx;
    }
    __syncthreads();

    const int p  = t & 31;
    const int cg = t >> 5;   // 8 channel groups
    const int n  = g0 / HW;
    const int hw = (g0 % HW) + p;
    const float* drow = dict + (size_t)idx_s[p] * CCH;
    const size_t obase = (size_t)n * CCH * HW + hw;

#pragma unroll 1
    for (int cp = 0; cp < 32; ++cp) {
        int c = cp * 8 + cg;
        float v = drow[c];
        size_t o = obase + (size_t)c * HW;
        out_emb[o]    = v;
        out_emb_pt[o] = v;
    }
}

extern "C" void kernel_launch(void* const* d_in, const int* in_sizes, int n_in,
                              void* d_out, int out_size, void* d_ws, size_t ws_size,
                              hipStream_t stream) {
    const float* x0   = (const float*)d_in[0];
    const float* x1   = (const float*)d_in[1];
    const float* dict = (const float*)d_in[2];
    float* out = (float*)d_out;

    // Workspace: norms (1024 f) | pdistA | pidxA | pdistB | pidxB  (each NPIX*NDT)
    float* norms  = (float*)d_ws;
    float* pdistA = norms + DDICT;
    int*   pidxA  = (int*)(pdistA + (size_t)NPIX * NDT);
    float* pdistB = (float*)(pidxA + (size_t)NPIX * NDT);
    int*   pidxB  = (int*)(pdistB + (size_t)NPIX * NDT);

    dict_norms_kernel<<<dim3(DDICT / 256), dim3(256), 0, stream>>>(dict, norms);

    dim3 g1(NPIX / TPX, NDT);
    vq_partial_kernel<<<g1, dim3(256), 0, stream>>>(x0, dict, norms, pdistA, pidxA);
    vq_partial_kernel<<<g1, dim3(256), 0, stream>>>(x1, dict, norms, pdistB, pidxB);

    dim3 g2(NPIX / 32);
    vq_finalize_kernel<<<g2, dim3(256), 0, stream>>>(pdistA, pidxA, dict,
                                                     out,
                                                     out + EMB_ELEMS,
                                                     out + 2 * EMB_ELEMS);
    vq_finalize_kernel<<<g2, dim3(256), 0, stream>>>(pdistB, pidxB, dict,
                                                     out + SEC_ELEMS,
                                                     out + SEC_ELEMS + EMB_ELEMS,
                                                     out + SEC_ELEMS + 2 * EMB_ELEMS);
}